// Round 9
// baseline (179.094 us; speedup 1.0000x reference)
//
#include <hip/hip_runtime.h>

// --- MFMA fp16 LSTM, Round 20: compile-time parity, immediate LDS addressing ---
// r12 skeleton (95.6us, 29 phases, verified): 512-thr blocks, 2/CU.
// Invariant r12-r19: phase ~7.9k cyc, VALU-busy ~4.3k/SIMD-phase under ALL
// scheduling/topology changes (r13 group-alt, r15 stagger, r17 half-reads/
// half-waves, r18 4-domain [infeasible], r19 data-order anti-phase [no-op by
// construction]). Hand count of essential ops ~2.8k/SIMD-phase vs 4.3k busy:
// gap ~= runtime-parity addressing (20 LDS ops/wave-phase recompute VGPR
// addrs off runtime plane ptrs) + runtime doL0/doL1 branches in a rolled loop.
// r20 (math/layout bit-identical to r12):
//  (a) peel p=-1/26/27, 2x-unroll main loop -> pr/pr1 LITERAL -> immediate
//      LDS offsets off loop-invariant regs; no runtime branches in loop.
//  (b) x staging by k-pairs: thread covers (col, k=2m,2m+1) -> one dwordx2
//      load + 2 cvt + one ds_write_b32 (was 2 loads + 2 cvt + 2 u16 writes);
//      constant rows k>=28 written once at init for both parities.
// Phase p: layer1(t=p) reads h0(p),h1(p-1); layer0(t=p+1) reads x(p+1),h0(p);
// 29 barriers. Weights pre-scaled (i/f/o by -log2e, g by +2log2e) -> bare
// exp2; gate math = verified 7-trans form. Planes frag-linear.

typedef _Float16 half8  __attribute__((ext_vector_type(8)));
typedef _Float16 half2v __attribute__((ext_vector_type(2)));
typedef float floatx4 __attribute__((ext_vector_type(4)));

#define NFRAG 112
#define WS_BIAS_OFF (NFRAG * 1024)
#define K2 2.8853900817779268f      // 2*log2(e)

#if __has_builtin(__builtin_amdgcn_exp2f)
#define EXP2(v) __builtin_amdgcn_exp2f(v)
#else
#define EXP2(v) __expf(0.6931471805599453f * (v))
#endif
#define RCP(v) __builtin_amdgcn_rcpf(v)

__global__ void prep_kernel(const float* __restrict__ Wih0, const float* __restrict__ Whh0,
                            const float* __restrict__ bih0, const float* __restrict__ bhh0,
                            const float* __restrict__ Wih1, const float* __restrict__ Whh1,
                            const float* __restrict__ bih1, const float* __restrict__ bhh1,
                            _Float16* __restrict__ wA, float* __restrict__ wBias) {
    int idx = blockIdx.x * blockDim.x + threadIdx.x;
    if (idx < NFRAG * 512) {
        int f = idx >> 9, slot = idx & 511;
        int lane = slot >> 3, j = slot & 7;
        int mt, kt, layer;
        if (f < 48) { layer = 0; mt = f / 3; kt = f % 3; }
        else        { layer = 1; int f2 = f - 48; mt = f2 >> 2; kt = f2 & 3; }
        int m = mt * 16 + (lane & 15);
        int k = kt * 32 + (lane >> 4) * 8 + j;
        int u = m >> 2, g = m & 3;
        int row = g * 64 + u;
        float v;
        if (layer == 0) {
            if (k < 28)       v = Wih0[row * 28 + k];
            else if (k == 28) v = bih0[row] + bhh0[row];
            else if (k < 32)  v = 0.f;
            else              v = Whh0[row * 64 + (k - 32)];
        } else {
            if (k < 64)       v = Wih1[row * 64 + k];
            else              v = Whh1[row * 64 + (k - 64)];
        }
        float s = (g == 2) ? K2 : -1.4426950408889634f;
        wA[idx] = (_Float16)(v * s);
    } else if (idx < NFRAG * 512 + 256) {
        int m = idx - NFRAG * 512;
        int g = m & 3;
        int row = g * 64 + (m >> 2);
        float s = (g == 2) ? K2 : -1.4426950408889634f;
        wBias[m] = (bih1[row] + bhh1[row]) * s;
    }
}

// Breadth-first N-tile gate batch on PRE-SCALED accs (r12-verified form).
// cn = [c*pg*pi + (eg-1)*pf] / (pf*pg*pi)  (1 rcp); h = (ec-1)/(ec*po+po).
template <int N>
__device__ __forceinline__ void gate_batch(const floatx4* acc, float* c,
                                           _Float16* const* planes, const int* offs) {
    float ei[N], ef[N], eg[N], eo[N];
    #pragma unroll
    for (int i = 0; i < N; ++i) {
        floatx4 a = acc[i];
        ei[i] = EXP2(a[0]);
        ef[i] = EXP2(a[1]);
        eg[i] = EXP2(a[2]);
        eo[i] = EXP2(a[3]);
    }
    float num[N], rd[N], po[N];
    #pragma unroll
    for (int i = 0; i < N; ++i) {
        float pi = 1.0f + ei[i];
        float pf = 1.0f + ef[i];
        float pg = 1.0f + eg[i];
        po[i] = 1.0f + eo[i];
        float m = pg * pi;
        num[i] = c[i] * m + (eg[i] - 1.0f) * pf;
        rd[i]  = RCP(pf * m);
    }
    float ec[N];
    #pragma unroll
    for (int i = 0; i < N; ++i) {
        float cn = num[i] * rd[i];
        c[i] = cn;
        ec[i] = EXP2(K2 * cn);
    }
    #pragma unroll
    for (int i = 0; i < N; ++i) {
        float r2 = RCP(ec[i] * po[i] + po[i]);
        planes[i][offs[i]] = (_Float16)((ec[i] - 1.0f) * r2);
    }
}

__launch_bounds__(512, 4)
__global__ void lstm_mfma(const float* __restrict__ x,
                          const _Float16* __restrict__ wA,
                          const float* __restrict__ wBias,
                          const float* __restrict__ Wlin, const float* __restrict__ blin,
                          float* __restrict__ out) {
    __shared__ __align__(16) _Float16 h0p[2][2048];  // [parity][frag-linear]
    __shared__ __align__(16) _Float16 h1p[2][2048];
    __shared__ __align__(16) _Float16 xb[2][1024];
    __shared__ float wlin_s[640];
    __shared__ float blin_s[10];

    const int lane = threadIdx.x;
    const int w    = threadIdx.y;      // 0..7
    const int tid  = w * 64 + lane;
    const int quad = lane >> 4;
    const int col  = lane & 15;
    const int l8   = lane * 8;

    // ---- A fragments: wave owns m-tiles MT = 2w+j, units u = MT*4+quad ----
    half8 A0[2][3], A1[2][4];
    floatx4 bias1[2];
    int woff[2][2];                    // [j][in] full h-write offsets
    #pragma unroll
    for (int j = 0; j < 2; ++j) {
        const int MT = 2 * w + j;
        #pragma unroll
        for (int kt = 0; kt < 3; ++kt)
            A0[j][kt] = *(const half8*)(wA + (MT * 3 + kt) * 512 + l8);
        #pragma unroll
        for (int kt = 0; kt < 4; ++kt)
            A1[j][kt] = *(const half8*)(wA + (48 + MT * 4 + kt) * 512 + l8);
        const int u = MT * 4 + quad;
        bias1[j] = *(const floatx4*)(wBias + u * 4);
        const int hwr0 = (u >> 5) * 512 + (((u >> 3) & 3) * 16 + col) * 8 + (u & 7);
        woff[j][0] = hwr0;
        woff[j][1] = hwr0 + 1024;
    }

    // ---- x staging (k-pair scheme): thread = (scol 0..31, sm 0..15) ----
    const int scol = tid >> 4;
    const int sm   = tid & 15;
    const int k0   = 2 * sm;
    const bool svalid = (sm < 14);     // k0 < 28
    const int sin  = scol >> 4;        // n-half
    const int scl  = scol & 15;
    const int xstg = (sin << 9) + ((k0 >> 3) * 16 + scl) * 8 + (k0 & 7);
    const float* xptr = x + (blockIdx.x * 32 + scol) * 784 + k0;

    // ---- init: zero parity-1 planes; constant xb rows both parities; x(0) ----
    {
        ((int*)&h0p[1][0])[tid * 2 + 0] = 0;
        ((int*)&h0p[1][0])[tid * 2 + 1] = 0;
        ((int*)&h1p[1][0])[tid * 2 + 0] = 0;
        ((int*)&h1p[1][0])[tid * 2 + 1] = 0;
        if (!svalid) {                 // k0 = 28 or 30: t-invariant rows
            half2v cv;
            cv[0] = (sm == 14) ? (_Float16)1.0f : (_Float16)0.0f;
            cv[1] = (_Float16)0.0f;
            *(half2v*)&xb[0][xstg] = cv;
            *(half2v*)&xb[1][xstg] = cv;
        } else {
            float2 xv = *(const float2*)xptr;   // t = 0
            half2v hv;
            hv[0] = (_Float16)xv.x;
            hv[1] = (_Float16)xv.y;
            *(half2v*)&xb[0][xstg] = hv;
        }
        xptr += 28;                    // -> t = 1
    }
    __syncthreads();

    float c0[2][2] = {{0.f, 0.f}, {0.f, 0.f}};   // [j][in]
    float c1[2][2] = {{0.f, 0.f}, {0.f, 0.f}};

// One phase with LITERAL parity PR and literal DOL0/DOL1/DOSTAGE.
#define PHASE(PR, DOL0, DOL1, DOSTAGE)                                              \
    {                                                                               \
        float2 xv2 = {0.f, 0.f};                                                    \
        if ((DOSTAGE) && svalid) xv2 = *(const float2*)xptr;                        \
        half8 bx[2], bh0[2][2];                                                     \
        if (DOL0) {                                                                 \
            bx[0] = *(const half8*)&xb[(PR) ^ 1][l8];                               \
            bx[1] = *(const half8*)&xb[(PR) ^ 1][512 + l8];                         \
        }                                                                           \
        _Pragma("unroll")                                                           \
        for (int kt = 0; kt < 2; ++kt) {                                            \
            bh0[kt][0] = *(const half8*)&h0p[PR][kt * 512 + l8];                    \
            bh0[kt][1] = *(const half8*)&h0p[PR][1024 + kt * 512 + l8];             \
        }                                                                           \
        floatx4 acc0[2][2], acc1[2][2];                                             \
        if (DOL0) {                                                                 \
            _Pragma("unroll")                                                       \
            for (int j = 0; j < 2; ++j)                                             \
                _Pragma("unroll")                                                   \
                for (int in = 0; in < 2; ++in) {                                    \
                    acc0[j][in] = __builtin_amdgcn_mfma_f32_16x16x32_f16(           \
                        A0[j][0], bx[in], (floatx4){0.f, 0.f, 0.f, 0.f}, 0, 0, 0);  \
                    _Pragma("unroll")                                               \
                    for (int kt = 0; kt < 2; ++kt)                                  \
                        acc0[j][in] = __builtin_amdgcn_mfma_f32_16x16x32_f16(       \
                            A0[j][kt + 1], bh0[kt][in], acc0[j][in], 0, 0, 0);      \
                }                                                                   \
        }                                                                           \
        if (DOL1) {                                                                 \
            _Pragma("unroll")                                                       \
            for (int j = 0; j < 2; ++j)                                             \
                _Pragma("unroll")                                                   \
                for (int in = 0; in < 2; ++in) {                                    \
                    acc1[j][in] = bias1[j];                                         \
                    _Pragma("unroll")                                               \
                    for (int kt = 0; kt < 2; ++kt)                                  \
                        acc1[j][in] = __builtin_amdgcn_mfma_f32_16x16x32_f16(       \
                            A1[j][kt], bh0[kt][in], acc1[j][in], 0, 0, 0);          \
                }                                                                   \
            half8 bh1[2][2];                                                        \
            _Pragma("unroll")                                                       \
            for (int kt = 0; kt < 2; ++kt) {                                        \
                bh1[kt][0] = *(const half8*)&h1p[(PR) ^ 1][kt * 512 + l8];          \
                bh1[kt][1] = *(const half8*)&h1p[(PR) ^ 1][1024 + kt * 512 + l8];   \
            }                                                                       \
            _Pragma("unroll")                                                       \
            for (int j = 0; j < 2; ++j)                                             \
                _Pragma("unroll")                                                   \
                for (int kt = 0; kt < 2; ++kt)                                      \
                    _Pragma("unroll")                                               \
                    for (int in = 0; in < 2; ++in)                                  \
                        acc1[j][in] = __builtin_amdgcn_mfma_f32_16x16x32_f16(       \
                            A1[j][kt + 2], bh1[kt][in], acc1[j][in], 0, 0, 0);      \
        }                                                                           \
        if ((DOL0) && (DOL1)) {                                                     \
            floatx4 a8[8] = {acc0[0][0], acc0[0][1], acc0[1][0], acc0[1][1],        \
                             acc1[0][0], acc1[0][1], acc1[1][0], acc1[1][1]};       \
            float   cc[8] = {c0[0][0], c0[0][1], c0[1][0], c0[1][1],                \
                             c1[0][0], c1[0][1], c1[1][0], c1[1][1]};               \
            _Float16* pl[8] = {h0p[(PR) ^ 1], h0p[(PR) ^ 1], h0p[(PR) ^ 1],         \
                               h0p[(PR) ^ 1], h1p[PR], h1p[PR], h1p[PR], h1p[PR]};  \
            int offs[8] = {woff[0][0], woff[0][1], woff[1][0], woff[1][1],          \
                           woff[0][0], woff[0][1], woff[1][0], woff[1][1]};         \
            gate_batch<8>(a8, cc, pl, offs);                                        \
            c0[0][0] = cc[0]; c0[0][1] = cc[1]; c0[1][0] = cc[2]; c0[1][1] = cc[3]; \
            c1[0][0] = cc[4]; c1[0][1] = cc[5]; c1[1][0] = cc[6]; c1[1][1] = cc[7]; \
        } else if (DOL0) {                                                          \
            floatx4 a4[4] = {acc0[0][0], acc0[0][1], acc0[1][0], acc0[1][1]};       \
            float   cc[4] = {c0[0][0], c0[0][1], c0[1][0], c0[1][1]};               \
            _Float16* pl[4] = {h0p[(PR) ^ 1], h0p[(PR) ^ 1],                        \
                               h0p[(PR) ^ 1], h0p[(PR) ^ 1]};                       \
            int offs[4] = {woff[0][0], woff[0][1], woff[1][0], woff[1][1]};         \
            gate_batch<4>(a4, cc, pl, offs);                                        \
            c0[0][0] = cc[0]; c0[0][1] = cc[1]; c0[1][0] = cc[2]; c0[1][1] = cc[3]; \
        } else {                                                                    \
            floatx4 a4[4] = {acc1[0][0], acc1[0][1], acc1[1][0], acc1[1][1]};       \
            float   cc[4] = {c1[0][0], c1[0][1], c1[1][0], c1[1][1]};               \
            _Float16* pl[4] = {h1p[PR], h1p[PR], h1p[PR], h1p[PR]};                 \
            int offs[4] = {woff[0][0], woff[0][1], woff[1][0], woff[1][1]};         \
            gate_batch<4>(a4, cc, pl, offs);                                        \
            c1[0][0] = cc[0]; c1[0][1] = cc[1]; c1[1][0] = cc[2]; c1[1][1] = cc[3]; \
        }                                                                           \
        if (DOSTAGE) {                                                              \
            if (svalid) {                                                           \
                half2v hv;                                                          \
                hv[0] = (_Float16)xv2.x;                                            \
                hv[1] = (_Float16)xv2.y;                                            \
                *(half2v*)&xb[PR][xstg] = hv;                                       \
            }                                                                       \
            xptr += 28;                                                            \
        }                                                                           \
        __syncthreads();                                                            \
    }

    PHASE(1, true, false, true)        // p = -1
    for (int i = 0; i < 13; ++i) {     // p = 0..25
        PHASE(0, true, true, true)
        PHASE(1, true, true, true)
    }
    PHASE(0, true, true, false)        // p = 26
    PHASE(1, false, true, false)       // p = 27
#undef PHASE

    // ---- epilogue: out = h1(27) @ Wlin^T + blin ----
    wlin_s[tid] = Wlin[tid];
    if (tid < 128) wlin_s[512 + tid] = Wlin[512 + tid];
    if (tid < 10)  blin_s[tid] = blin[tid];
    __syncthreads();
    if (tid < 320) {
        int b = tid / 10, o = tid - b * 10;
        float a = blin_s[o];
        #pragma unroll 8
        for (int uu = 0; uu < 64; ++uu) {
            float hv = (float)h1p[1][((b >> 4) * 2 + (uu >> 5)) * 512 + (((uu >> 3) & 3) * 16 + (b & 15)) * 8 + (uu & 7)];
            a += wlin_s[o * 64 + uu] * hv;
        }
        out[(blockIdx.x * 32 + b) * 10 + o] = a;
    }
}

extern "C" void kernel_launch(void* const* d_in, const int* in_sizes, int n_in,
                              void* d_out, int out_size, void* d_ws, size_t ws_size,
                              hipStream_t stream) {
    const float* x    = (const float*)d_in[0];
    const float* Wih0 = (const float*)d_in[1];
    const float* Whh0 = (const float*)d_in[2];
    const float* bih0 = (const float*)d_in[3];
    const float* bhh0 = (const float*)d_in[4];
    const float* Wih1 = (const float*)d_in[5];
    const float* Whh1 = (const float*)d_in[6];
    const float* bih1 = (const float*)d_in[7];
    const float* bhh1 = (const float*)d_in[8];
    const float* Wlin = (const float*)d_in[9];
    const float* blin = (const float*)d_in[10];
    float* out = (float*)d_out;

    _Float16* wA    = (_Float16*)d_ws;
    float*    wBias = (float*)((char*)d_ws + WS_BIAS_OFF);

    prep_kernel<<<225, 256, 0, stream>>>(Wih0, Whh0, bih0, bhh0,
                                         Wih1, Whh1, bih1, bhh1, wA, wBias);
    lstm_mfma<<<512, dim3(64, 8), 0, stream>>>(x, wA, wBias, Wlin, blin, out);
}